// Round 1
// baseline (524.611 us; speedup 1.0000x reference)
//
#include <hip/hip_runtime.h>
#include <stdint.h>

// Problem constants (B=4, L=2048, D=2048)
#define B_DIM 4
#define L_DIM 2048
#define D_DIM 2048
#define M_DIM 8192              // B*L token rows
#define K_DIM 2048
#define N_DIM 2048
#define WELEM (D_DIM * D_DIM)   // 4194304 elements per weight
#define CHUNK 32
#define NCH (L_DIM / CHUNK)     // 64 chunks per sequence

typedef int v4i __attribute__((ext_vector_type(4)));

#define AS1 __attribute__((address_space(1)))
#define AS3 __attribute__((address_space(3)))

__device__ __forceinline__ void gl_lds16(const void* g, void* l) {
    // async global->LDS, 16B per lane; LDS dst = wave-uniform base + lane*16
    __builtin_amdgcn_global_load_lds((AS1 void*)g, (AS3 void*)l, 16, 0, 0);
}

__device__ __forceinline__ float sigmoidf_(float x) { return 1.0f / (1.0f + expf(-x)); }

// ---------------- block reductions (256 threads = 4 waves) ----------------
__device__ __forceinline__ float block_sum256(float v) {
#pragma unroll
    for (int off = 32; off > 0; off >>= 1) v += __shfl_down(v, off);
    __shared__ float sb[4];
    int lane = threadIdx.x & 63, wv = threadIdx.x >> 6;
    __syncthreads();
    if (lane == 0) sb[wv] = v;
    __syncthreads();
    return sb[0] + sb[1] + sb[2] + sb[3];
}

__device__ __forceinline__ void block_sum_max256(float& s, float& m) {
#pragma unroll
    for (int off = 32; off > 0; off >>= 1) {
        s += __shfl_down(s, off);
        m = fmaxf(m, __shfl_down(m, off));
    }
    __shared__ float sb2[8];
    int lane = threadIdx.x & 63, wv = threadIdx.x >> 6;
    __syncthreads();
    if (lane == 0) { sb2[wv] = s; sb2[4 + wv] = m; }
    __syncthreads();
    s = sb2[0] + sb2[1] + sb2[2] + sb2[3];
    m = fmaxf(fmaxf(sb2[4], sb2[5]), fmaxf(sb2[6], sb2[7]));
}

// ---------------- weight stats: mean|W| per weight ----------------
// stage 1: 512 blocks (128 per weight), partial sums
__global__ void wstats1(const float* __restrict__ w0, const float* __restrict__ w1,
                        const float* __restrict__ w2, const float* __restrict__ w3,
                        float* __restrict__ wpart) {
    int w = blockIdx.x >> 7;
    int slice = blockIdx.x & 127;
    const float* W = (w == 0) ? w0 : ((w == 1) ? w1 : ((w == 2) ? w2 : w3));
    const float4* p = (const float4*)(W + (size_t)slice * (WELEM / 128));
    float s = 0.f;
    for (int i = threadIdx.x; i < (WELEM / 128 / 4); i += 256) {
        float4 v = p[i];
        s += fabsf(v.x) + fabsf(v.y) + fabsf(v.z) + fabsf(v.w);
    }
    s = block_sum256(s);
    if (threadIdx.x == 0) wpart[blockIdx.x] = s;
}

// stage 2: one block; wave w reduces weight w's 128 partials.
// wdeq[w] = clip(mean|W|, 1e-5) = 1/ws  (the dequant factor)
__global__ void wstats2(const float* __restrict__ wpart, float* __restrict__ wdeq) {
    int w = threadIdx.x >> 6;
    int lane = threadIdx.x & 63;
    float s = wpart[w * 128 + lane] + wpart[w * 128 + 64 + lane];
#pragma unroll
    for (int off = 32; off > 0; off >>= 1) s += __shfl_down(s, off);
    if (lane == 0) wdeq[w] = fmaxf(s * (1.0f / (float)WELEM), 1e-5f);
}

// ---------------- weight ternary quantization ----------------
__global__ void wquant(const float* __restrict__ w0, const float* __restrict__ w1,
                       const float* __restrict__ w2, const float* __restrict__ w3,
                       const float* __restrict__ wdeq, int8_t* __restrict__ wq) {
    size_t idx = (size_t)blockIdx.x * 256 + threadIdx.x;   // one float4 group each
    int w = (int)(idx >> 20);                               // WELEM/4 = 2^20 groups per weight
    size_t g = idx & ((1u << 20) - 1);
    const float* W = (w == 0) ? w0 : ((w == 1) ? w1 : ((w == 2) ? w2 : w3));
    float inv = 1.0f / wdeq[w];                             // = ws
    float4 v = ((const float4*)W)[g];
    int q0 = (int)rintf(v.x * inv); q0 = q0 < -1 ? -1 : (q0 > 1 ? 1 : q0);
    int q1 = (int)rintf(v.y * inv); q1 = q1 < -1 ? -1 : (q1 > 1 ? 1 : q1);
    int q2 = (int)rintf(v.z * inv); q2 = q2 < -1 ? -1 : (q2 > 1 ? 1 : q2);
    int q3 = (int)rintf(v.w * inv); q3 = q3 < -1 ? -1 : (q3 > 1 ? 1 : q3);
    uint32_t p = (uint32_t)(q0 & 0xff) | ((uint32_t)(q1 & 0xff) << 8) |
                 ((uint32_t)(q2 & 0xff) << 16) | ((uint32_t)(q3 & 0xff) << 24);
    ((uint32_t*)(wq + (size_t)w * WELEM))[g] = p;
}

// ---------------- activation rmsnorm + int8 quant (per token row) ----------------
__global__ void act_quant(const float* __restrict__ x, int8_t* __restrict__ xq,
                          float* __restrict__ adeq) {
    int row = blockIdx.x, tid = threadIdx.x;
    const float4* xr = (const float4*)(x + (size_t)row * D_DIM);
    float4 a = xr[2 * tid], b = xr[2 * tid + 1];
    float v[8] = {a.x, a.y, a.z, a.w, b.x, b.y, b.z, b.w};
    float ss = 0.f, mx = 0.f;
#pragma unroll
    for (int j = 0; j < 8; j++) { ss += v[j] * v[j]; mx = fmaxf(mx, fabsf(v[j])); }
    block_sum_max256(ss, mx);
    float inv = rsqrtf(ss * (1.0f / (float)D_DIM) + 1e-5f);
    float anc = fmaxf(mx * inv, 1e-5f);      // max|xn| clipped
    float s = 127.0f / anc;
    if (tid == 0) adeq[row] = anc * (1.0f / 127.0f);
    float sc = inv * s;
    int q[8];
#pragma unroll
    for (int j = 0; j < 8; j++) {
        int t = (int)rintf(v[j] * sc);
        q[j] = t < -128 ? -128 : (t > 127 ? 127 : t);
    }
    uint32_t lo = (uint32_t)(q[0] & 0xff) | ((uint32_t)(q[1] & 0xff) << 8) |
                  ((uint32_t)(q[2] & 0xff) << 16) | ((uint32_t)(q[3] & 0xff) << 24);
    uint32_t hi = (uint32_t)(q[4] & 0xff) | ((uint32_t)(q[5] & 0xff) << 8) |
                  ((uint32_t)(q[6] & 0xff) << 16) | ((uint32_t)(q[7] & 0xff) << 24);
    ((uint2*)(xq + (size_t)row * D_DIM))[tid] = make_uint2(lo, hi);
}

// ---------------- int8 x ternary GEMM: C[m,n] = sum_k A[m,k]*B[n,k], dequantized ----
// 128x128 tile, BK=64 bytes, 256 threads (4 waves, 2x2 wave grid, 64x64 each)
#define BM 128
#define BN 128
#define BKB 64

__global__ __launch_bounds__(256) void gemm_i8(
    const int8_t* __restrict__ A, const int8_t* __restrict__ Bw,
    const float* __restrict__ adeq, const float* __restrict__ wdeq, int widx,
    float* __restrict__ Cout) {
    __shared__ int8_t sA[BM * BKB];
    __shared__ int8_t sB[BN * BKB];
    int m0 = blockIdx.y * BM;
    int n0 = blockIdx.x * BN;
    int lane = threadIdx.x & 63;
    int wv = threadIdx.x >> 6;
    int wm = (wv >> 1) * 64;
    int wn = (wv & 1) * 64;

    const v4i vzero = {0, 0, 0, 0};
    v4i acc[4][4];
#pragma unroll
    for (int i = 0; i < 4; i++)
#pragma unroll
        for (int j = 0; j < 4; j++) acc[i][j] = vzero;

    // staging: wave wv covers rows [wv*16, wv*16+16) and [64+wv*16, ...)
    int rA = lane >> 2;             // row within 16-row group
    int cA = (lane & 3) * 16;       // byte col within 64
    const int8_t* Ablk = A + (size_t)m0 * K_DIM;
    const int8_t* Bblk = Bw + (size_t)n0 * K_DIM;
    int qq = lane >> 4;             // quad
    int mr = lane & 15;

    for (int kt = 0; kt < K_DIM; kt += BKB) {
        gl_lds16(Ablk + (size_t)(wv * 16 + rA) * K_DIM + kt + cA, sA + (wv * 16) * BKB);
        gl_lds16(Ablk + (size_t)(64 + wv * 16 + rA) * K_DIM + kt + cA, sA + (64 + wv * 16) * BKB);
        gl_lds16(Bblk + (size_t)(wv * 16 + rA) * K_DIM + kt + cA, sB + (wv * 16) * BKB);
        gl_lds16(Bblk + (size_t)(64 + wv * 16 + rA) * K_DIM + kt + cA, sB + (64 + wv * 16) * BKB);
        __syncthreads();   // drains vmcnt before barrier -> staged data visible

        v4i afrag[4], bfrag[4];
#pragma unroll
        for (int i = 0; i < 4; i++)
            afrag[i] = *(const v4i*)(sA + (size_t)(wm + i * 16 + mr) * BKB + qq * 16);
#pragma unroll
        for (int j = 0; j < 4; j++)
            bfrag[j] = *(const v4i*)(sB + (size_t)(wn + j * 16 + mr) * BKB + qq * 16);
#pragma unroll
        for (int i = 0; i < 4; i++)
#pragma unroll
            for (int j = 0; j < 4; j++)
                acc[i][j] = __builtin_amdgcn_mfma_i32_16x16x64_i8(afrag[i], bfrag[j], acc[i][j], 0, 0, 0);
        __syncthreads();   // protect LDS from next iteration's staging
    }

    float wsc = wdeq[widx];
    int cc = lane & 15;
#pragma unroll
    for (int i = 0; i < 4; i++) {
#pragma unroll
        for (int r = 0; r < 4; r++) {
            int row = m0 + wm + i * 16 + qq * 4 + r;   // C/D: row = quad*4 + reg
            float rs = adeq[row] * wsc;
            float* crow = Cout + (size_t)row * N_DIM + n0 + wn + cc;
#pragma unroll
            for (int j = 0; j < 4; j++) crow[j * 16] = (float)acc[i][j][r] * rs;
        }
    }
}

// ---------------- i/f activations (in place): f=sigmoid(fL); i=silu(iL)*(1-f) ------
__global__ void act_if(float* __restrict__ iL, float* __restrict__ fL) {
    size_t idx = (size_t)blockIdx.x * 256 + threadIdx.x;
    float4 vi = ((float4*)iL)[idx];
    float4 vf = ((float4*)fL)[idx];
    float f0 = sigmoidf_(vf.x), f1 = sigmoidf_(vf.y), f2 = sigmoidf_(vf.z), f3 = sigmoidf_(vf.w);
    vi.x = vi.x * sigmoidf_(vi.x) * (1.0f - f0);
    vi.y = vi.y * sigmoidf_(vi.y) * (1.0f - f1);
    vi.z = vi.z * sigmoidf_(vi.z) * (1.0f - f2);
    vi.w = vi.w * sigmoidf_(vi.w) * (1.0f - f3);
    ((float4*)iL)[idx] = vi;
    ((float4*)fL)[idx] = make_float4(f0, f1, f2, f3);
}

// ---------------- chunked scan: h_t = f_t*h_{t-1} + i_t along t per (b,d) ----------
__global__ void scan1(const float* __restrict__ i_, const float* __restrict__ f_,
                      float* __restrict__ Fc, float* __restrict__ Ic) {
    int idx = blockIdx.x * 256 + threadIdx.x;   // 4*64*2048
    int d = idx & (D_DIM - 1);
    int c = (idx >> 11) & (NCH - 1);
    int b = idx >> 17;
    size_t base = ((size_t)(b * L_DIM + c * CHUNK)) * D_DIM + d;
    float F = 1.f, h = 0.f;
#pragma unroll 4
    for (int t = 0; t < CHUNK; t++) {
        float fv = f_[base + (size_t)t * D_DIM];
        float iv = i_[base + (size_t)t * D_DIM];
        h = fv * h + iv;
        F *= fv;
    }
    size_t ci = ((size_t)b * NCH + c) * D_DIM + d;
    Fc[ci] = F;
    Ic[ci] = h;
}

__global__ void scan2(const float* __restrict__ Fc, const float* __restrict__ Ic,
                      float* __restrict__ Hc) {
    int idx = blockIdx.x * 256 + threadIdx.x;   // 8192
    int d = idx & (D_DIM - 1);
    int b = idx >> 11;
    float h = 0.f;
    for (int c = 0; c < NCH; c++) {
        size_t ci = ((size_t)b * NCH + c) * D_DIM + d;
        Hc[ci] = h;
        h = Fc[ci] * h + Ic[ci];
    }
}

__global__ void scan3(const float* __restrict__ i_, const float* __restrict__ f_,
                      const float* __restrict__ Hc, float* __restrict__ hout) {
    int idx = blockIdx.x * 256 + threadIdx.x;
    int d = idx & (D_DIM - 1);
    int c = (idx >> 11) & (NCH - 1);
    int b = idx >> 17;
    size_t base = ((size_t)(b * L_DIM + c * CHUNK)) * D_DIM + d;
    float h = Hc[((size_t)b * NCH + c) * D_DIM + d];
#pragma unroll 4
    for (int t = 0; t < CHUNK; t++) {
        size_t a = base + (size_t)t * D_DIM;
        h = f_[a] * h + i_[a];
        hout[a] = h;
    }
}

// ---------------- g-path: o = rmsnorm(g)*gw * h*sigmoid(h); rmsnorm+quant o ---------
__global__ void gout_quant(const float* __restrict__ gL, const float* __restrict__ h,
                           const float* __restrict__ gw, int8_t* __restrict__ oq,
                           float* __restrict__ odeq) {
    int row = blockIdx.x, tid = threadIdx.x;
    const float4* gr = (const float4*)(gL + (size_t)row * D_DIM);
    const float4* hr = (const float4*)(h + (size_t)row * D_DIM);
    const float4* wr = (const float4*)gw;
    float4 g0 = gr[2 * tid], g1 = gr[2 * tid + 1];
    float gv[8] = {g0.x, g0.y, g0.z, g0.w, g1.x, g1.y, g1.z, g1.w};
    float ss = 0.f;
#pragma unroll
    for (int j = 0; j < 8; j++) ss += gv[j] * gv[j];
    float ssg = block_sum256(ss);
    float invg = rsqrtf(ssg * (1.0f / (float)D_DIM) + 1e-5f);

    float4 h0 = hr[2 * tid], h1 = hr[2 * tid + 1];
    float4 w0 = wr[2 * tid], w1 = wr[2 * tid + 1];
    float hv[8] = {h0.x, h0.y, h0.z, h0.w, h1.x, h1.y, h1.z, h1.w};
    float wv[8] = {w0.x, w0.y, w0.z, w0.w, w1.x, w1.y, w1.z, w1.w};
    float o[8];
    float sso = 0.f, amax = 0.f;
#pragma unroll
    for (int j = 0; j < 8; j++) {
        o[j] = gv[j] * invg * wv[j] * hv[j] * sigmoidf_(hv[j]);
        sso += o[j] * o[j];
        amax = fmaxf(amax, fabsf(o[j]));
    }
    block_sum_max256(sso, amax);
    float invo = rsqrtf(sso * (1.0f / (float)D_DIM) + 1e-5f);
    float anc = fmaxf(amax * invo, 1e-5f);
    float s = 127.0f / anc;
    if (tid == 0) odeq[row] = anc * (1.0f / 127.0f);
    float sc = invo * s;
    int q[8];
#pragma unroll
    for (int j = 0; j < 8; j++) {
        int t = (int)rintf(o[j] * sc);
        q[j] = t < -128 ? -128 : (t > 127 ? 127 : t);
    }
    uint32_t lo = (uint32_t)(q[0] & 0xff) | ((uint32_t)(q[1] & 0xff) << 8) |
                  ((uint32_t)(q[2] & 0xff) << 16) | ((uint32_t)(q[3] & 0xff) << 24);
    uint32_t hi = (uint32_t)(q[4] & 0xff) | ((uint32_t)(q[5] & 0xff) << 8) |
                  ((uint32_t)(q[6] & 0xff) << 16) | ((uint32_t)(q[7] & 0xff) << 24);
    ((uint2*)(oq + (size_t)row * D_DIM))[tid] = make_uint2(lo, hi);
}

// ---------------- driver ----------------
extern "C" void kernel_launch(void* const* d_in, const int* in_sizes, int n_in,
                              void* d_out, int out_size, void* d_ws, size_t ws_size,
                              hipStream_t stream) {
    const float* x  = (const float*)d_in[0];
    const float* Wi = (const float*)d_in[1];
    const float* Wf = (const float*)d_in[2];
    const float* Wg = (const float*)d_in[3];
    const float* Wo = (const float*)d_in[4];
    const float* gw = (const float*)d_in[5];
    float* out = (float*)d_out;

    char* ws = (char*)d_ws;
    float*  wdeq  = (float*)(ws + 0);                 // 4 floats: clip(mean|W|,1e-5)
    float*  wpart = (float*)(ws + 256);               // 512 partials
    float*  adeq  = (float*)(ws + 0x10000);           // 8192 per-row act dequant
    float*  odeq  = (float*)(ws + 0x20000);           // 8192 per-row o dequant
    int8_t* xq    = (int8_t*)(ws + 0x100000);         // 16MB int8 x; later reused as oq
    int8_t* wq    = (int8_t*)(ws + 0x1100000);        // 4 x 4MB ternary weights
    float*  Fc    = (float*)(ws + 0x2100000);         // 2MB chunk f-products
    float*  Ic    = (float*)(ws + 0x2300000);         // 2MB chunk partial h
    float*  Hc    = (float*)(ws + 0x2500000);         // 2MB chunk carries
    float*  bufI  = (float*)(ws + 0x4000000);         // 64MB: i_lin -> i -> g_lin
    float*  bufF  = (float*)(ws + 0x8000000);         // 64MB: f_lin -> f

    wstats1<<<512, 256, 0, stream>>>(Wi, Wf, Wg, Wo, wpart);
    wstats2<<<1, 256, 0, stream>>>(wpart, wdeq);
    wquant<<<16384, 256, 0, stream>>>(Wi, Wf, Wg, Wo, wdeq, wq);
    act_quant<<<M_DIM, 256, 0, stream>>>(x, xq, adeq);

    dim3 ggrid(N_DIM / BN, M_DIM / BM);
    gemm_i8<<<ggrid, 256, 0, stream>>>(xq, wq + 0 * (size_t)WELEM, adeq, wdeq, 0, bufI); // i_lin
    gemm_i8<<<ggrid, 256, 0, stream>>>(xq, wq + 1 * (size_t)WELEM, adeq, wdeq, 1, bufF); // f_lin

    act_if<<<16384, 256, 0, stream>>>(bufI, bufF);

    scan1<<<2048, 256, 0, stream>>>(bufI, bufF, Fc, Ic);
    scan2<<<32, 256, 0, stream>>>(Fc, Ic, Hc);
    scan3<<<2048, 256, 0, stream>>>(bufI, bufF, Hc, out);      // h -> d_out (scratch)

    gemm_i8<<<ggrid, 256, 0, stream>>>(xq, wq + 2 * (size_t)WELEM, adeq, wdeq, 2, bufI); // g_lin
    gout_quant<<<M_DIM, 256, 0, stream>>>(bufI, out, gw, xq /*as oq*/, odeq);
    gemm_i8<<<ggrid, 256, 0, stream>>>(xq /*oq*/, wq + 3 * (size_t)WELEM, odeq, wdeq, 3, out);

    (void)in_sizes; (void)n_in; (void)out_size; (void)ws_size;
}

// Round 2
// 492.955 us; speedup vs baseline: 1.0642x; 1.0642x over previous
//
#include <hip/hip_runtime.h>
#include <stdint.h>

// Problem constants (B=4, L=2048, D=2048)
#define B_DIM 4
#define L_DIM 2048
#define D_DIM 2048
#define M_DIM 8192              // B*L token rows
#define K_DIM 2048
#define N_DIM 2048
#define WELEM (D_DIM * D_DIM)   // 4194304 elements per weight
#define CHUNK 32
#define NCH (L_DIM / CHUNK)     // 64 chunks per sequence

typedef int v4i __attribute__((ext_vector_type(4)));
typedef unsigned short bfraw;   // bf16 bit pattern

#define AS1 __attribute__((address_space(1)))
#define AS3 __attribute__((address_space(3)))

__device__ __forceinline__ void gl_lds16(const void* g, void* l) {
    // async global->LDS, 16B per lane; LDS dst = wave-uniform base + lane*16
    __builtin_amdgcn_global_load_lds((AS1 void*)g, (AS3 void*)l, 16, 0, 0);
}

__device__ __forceinline__ float sigmoidf_(float x) { return 1.0f / (1.0f + expf(-x)); }

__device__ __forceinline__ float bf2f(bfraw u) {
    union { unsigned int i; float f; } c; c.i = ((unsigned int)u) << 16; return c.f;
}
__device__ __forceinline__ bfraw f2bf(float f) {
    union { float f; unsigned int i; } c; c.f = f;
    unsigned int lsb = (c.i >> 16) & 1;
    c.i += 0x7fffu + lsb;                   // round-to-nearest-even
    return (bfraw)(c.i >> 16);
}

__device__ __forceinline__ void store_out(float* p, float v) { *p = v; }
__device__ __forceinline__ void store_out(bfraw* p, float v) { *p = f2bf(v); }

// ---------------- block reductions (256 threads = 4 waves) ----------------
__device__ __forceinline__ float block_sum256(float v) {
#pragma unroll
    for (int off = 32; off > 0; off >>= 1) v += __shfl_down(v, off);
    __shared__ float sb[4];
    int lane = threadIdx.x & 63, wv = threadIdx.x >> 6;
    __syncthreads();
    if (lane == 0) sb[wv] = v;
    __syncthreads();
    return sb[0] + sb[1] + sb[2] + sb[3];
}

__device__ __forceinline__ void block_sum_max256(float& s, float& m) {
#pragma unroll
    for (int off = 32; off > 0; off >>= 1) {
        s += __shfl_down(s, off);
        m = fmaxf(m, __shfl_down(m, off));
    }
    __shared__ float sb2[8];
    int lane = threadIdx.x & 63, wv = threadIdx.x >> 6;
    __syncthreads();
    if (lane == 0) { sb2[wv] = s; sb2[4 + wv] = m; }
    __syncthreads();
    s = sb2[0] + sb2[1] + sb2[2] + sb2[3];
    m = fmaxf(fmaxf(sb2[4], sb2[5]), fmaxf(sb2[6], sb2[7]));
}

// ---------------- weight stats: mean|W| per weight ----------------
__global__ void wstats1(const float* __restrict__ w0, const float* __restrict__ w1,
                        const float* __restrict__ w2, const float* __restrict__ w3,
                        float* __restrict__ wpart) {
    int w = blockIdx.x >> 7;
    int slice = blockIdx.x & 127;
    const float* W = (w == 0) ? w0 : ((w == 1) ? w1 : ((w == 2) ? w2 : w3));
    const float4* p = (const float4*)(W + (size_t)slice * (WELEM / 128));
    float s = 0.f;
    for (int i = threadIdx.x; i < (WELEM / 128 / 4); i += 256) {
        float4 v = p[i];
        s += fabsf(v.x) + fabsf(v.y) + fabsf(v.z) + fabsf(v.w);
    }
    s = block_sum256(s);
    if (threadIdx.x == 0) wpart[blockIdx.x] = s;
}

__global__ void wstats2(const float* __restrict__ wpart, float* __restrict__ wdeq) {
    int w = threadIdx.x >> 6;
    int lane = threadIdx.x & 63;
    float s = wpart[w * 128 + lane] + wpart[w * 128 + 64 + lane];
#pragma unroll
    for (int off = 32; off > 0; off >>= 1) s += __shfl_down(s, off);
    if (lane == 0) wdeq[w] = fmaxf(s * (1.0f / (float)WELEM), 1e-5f);
}

// ---------------- weight ternary quantization ----------------
__global__ void wquant(const float* __restrict__ w0, const float* __restrict__ w1,
                       const float* __restrict__ w2, const float* __restrict__ w3,
                       const float* __restrict__ wdeq, int8_t* __restrict__ wq) {
    size_t idx = (size_t)blockIdx.x * 256 + threadIdx.x;   // one float4 group each
    int w = (int)(idx >> 20);                               // WELEM/4 = 2^20 groups per weight
    size_t g = idx & ((1u << 20) - 1);
    const float* W = (w == 0) ? w0 : ((w == 1) ? w1 : ((w == 2) ? w2 : w3));
    float inv = 1.0f / wdeq[w];                             // = ws
    float4 v = ((const float4*)W)[g];
    int q0 = (int)rintf(v.x * inv); q0 = q0 < -1 ? -1 : (q0 > 1 ? 1 : q0);
    int q1 = (int)rintf(v.y * inv); q1 = q1 < -1 ? -1 : (q1 > 1 ? 1 : q1);
    int q2 = (int)rintf(v.z * inv); q2 = q2 < -1 ? -1 : (q2 > 1 ? 1 : q2);
    int q3 = (int)rintf(v.w * inv); q3 = q3 < -1 ? -1 : (q3 > 1 ? 1 : q3);
    uint32_t p = (uint32_t)(q0 & 0xff) | ((uint32_t)(q1 & 0xff) << 8) |
                 ((uint32_t)(q2 & 0xff) << 16) | ((uint32_t)(q3 & 0xff) << 24);
    ((uint32_t*)(wq + (size_t)w * WELEM))[g] = p;
}

// ---------------- activation rmsnorm + int8 quant (per token row) ----------------
__global__ void act_quant(const float* __restrict__ x, int8_t* __restrict__ xq,
                          float* __restrict__ adeq) {
    int row = blockIdx.x, tid = threadIdx.x;
    const float4* xr = (const float4*)(x + (size_t)row * D_DIM);
    float4 a = xr[2 * tid], b = xr[2 * tid + 1];
    float v[8] = {a.x, a.y, a.z, a.w, b.x, b.y, b.z, b.w};
    float ss = 0.f, mx = 0.f;
#pragma unroll
    for (int j = 0; j < 8; j++) { ss += v[j] * v[j]; mx = fmaxf(mx, fabsf(v[j])); }
    block_sum_max256(ss, mx);
    float inv = rsqrtf(ss * (1.0f / (float)D_DIM) + 1e-5f);
    float anc = fmaxf(mx * inv, 1e-5f);      // max|xn| clipped
    float s = 127.0f / anc;
    if (tid == 0) adeq[row] = anc * (1.0f / 127.0f);
    float sc = inv * s;
    int q[8];
#pragma unroll
    for (int j = 0; j < 8; j++) {
        int t = (int)rintf(v[j] * sc);
        q[j] = t < -128 ? -128 : (t > 127 ? 127 : t);
    }
    uint32_t lo = (uint32_t)(q[0] & 0xff) | ((uint32_t)(q[1] & 0xff) << 8) |
                  ((uint32_t)(q[2] & 0xff) << 16) | ((uint32_t)(q[3] & 0xff) << 24);
    uint32_t hi = (uint32_t)(q[4] & 0xff) | ((uint32_t)(q[5] & 0xff) << 8) |
                  ((uint32_t)(q[6] & 0xff) << 16) | ((uint32_t)(q[7] & 0xff) << 24);
    ((uint2*)(xq + (size_t)row * D_DIM))[tid] = make_uint2(lo, hi);
}

// ---------------- int8 x ternary GEMM: C[m,n] = sum_k A[m,k]*B[n,k], dequantized ----
// 128x128 tile, BK=128 bytes, 256 threads (4 waves, 2x2 wave grid, 64x64 each)
#define BM 128
#define BN 128
#define BKB 128

template <typename OutT>
__global__ __launch_bounds__(256) void gemm_i8(
    const int8_t* __restrict__ A, const int8_t* __restrict__ Bw,
    const float* __restrict__ adeq, const float* __restrict__ wdeq, int widx,
    OutT* __restrict__ Cout) {
    __shared__ int8_t sA[BM * BKB];   // 16 KB
    __shared__ int8_t sB[BN * BKB];   // 16 KB
    int m0 = blockIdx.y * BM;
    int n0 = blockIdx.x * BN;
    int lane = threadIdx.x & 63;
    int wv = threadIdx.x >> 6;
    int wm = (wv >> 1) * 64;
    int wn = (wv & 1) * 64;

    const v4i vzero = {0, 0, 0, 0};
    v4i acc[4][4];
#pragma unroll
    for (int i = 0; i < 4; i++)
#pragma unroll
        for (int j = 0; j < 4; j++) acc[i][j] = vzero;

    // staging: one inst covers 8 rows x 128B; lane -> row = rb + (lane>>3), byte = (lane&7)*16
    int rS = lane >> 3;
    int cS = (lane & 7) * 16;
    const int8_t* Ablk = A + (size_t)m0 * K_DIM;
    const int8_t* Bblk = Bw + (size_t)n0 * K_DIM;
    int qq = lane >> 4;             // quad
    int mr = lane & 15;

    for (int kt = 0; kt < K_DIM; kt += BKB) {
#pragma unroll
        for (int g = 0; g < 4; g++) {
            int rb = wv * 8 + g * 32;
            gl_lds16(Ablk + (size_t)(rb + rS) * K_DIM + kt + cS, sA + rb * BKB);
            gl_lds16(Bblk + (size_t)(rb + rS) * K_DIM + kt + cS, sB + rb * BKB);
        }
        __syncthreads();   // drains vmcnt before barrier -> staged data visible

#pragma unroll
        for (int kk = 0; kk < 2; kk++) {
            v4i afrag[4], bfrag[4];
#pragma unroll
            for (int i = 0; i < 4; i++)
                afrag[i] = *(const v4i*)(sA + (size_t)(wm + i * 16 + mr) * BKB + kk * 64 + qq * 16);
#pragma unroll
            for (int j = 0; j < 4; j++)
                bfrag[j] = *(const v4i*)(sB + (size_t)(wn + j * 16 + mr) * BKB + kk * 64 + qq * 16);
#pragma unroll
            for (int i = 0; i < 4; i++)
#pragma unroll
                for (int j = 0; j < 4; j++)
                    acc[i][j] = __builtin_amdgcn_mfma_i32_16x16x64_i8(afrag[i], bfrag[j], acc[i][j], 0, 0, 0);
        }
        __syncthreads();   // protect LDS from next iteration's staging
    }

    float wsc = wdeq[widx];
    int cc = lane & 15;
#pragma unroll
    for (int i = 0; i < 4; i++) {
#pragma unroll
        for (int r = 0; r < 4; r++) {
            int row = m0 + wm + i * 16 + qq * 4 + r;   // C/D: row = quad*4 + reg
            float rs = adeq[row] * wsc;
            OutT* crow = Cout + (size_t)row * N_DIM + n0 + wn + cc;
#pragma unroll
            for (int j = 0; j < 4; j++) store_out(crow + j * 16, (float)acc[i][j][r] * rs);
        }
    }
}

// ---------------- chunked scan with fused activations ----------------
// f_t = sigmoid(fL_t); i_t = silu(iL_t)*(1-f_t); h_t = f_t*h_{t-1} + i_t
__global__ void scan1(const bfraw* __restrict__ iL, const bfraw* __restrict__ fL,
                      float* __restrict__ Fc, float* __restrict__ Ic) {
    int idx = blockIdx.x * 256 + threadIdx.x;   // 4*64*2048
    int d = idx & (D_DIM - 1);
    int c = (idx >> 11) & (NCH - 1);
    int b = idx >> 17;
    size_t base = ((size_t)(b * L_DIM + c * CHUNK)) * D_DIM + d;
    float F = 1.f, h = 0.f;
#pragma unroll 4
    for (int t = 0; t < CHUNK; t++) {
        float fr = bf2f(fL[base + (size_t)t * D_DIM]);
        float ir = bf2f(iL[base + (size_t)t * D_DIM]);
        float fv = sigmoidf_(fr);
        float iv = ir * sigmoidf_(ir) * (1.0f - fv);
        h = fv * h + iv;
        F *= fv;
    }
    size_t ci = ((size_t)b * NCH + c) * D_DIM + d;
    Fc[ci] = F;
    Ic[ci] = h;
}

__global__ void scan2(const float* __restrict__ Fc, const float* __restrict__ Ic,
                      float* __restrict__ Hc) {
    int idx = blockIdx.x * 256 + threadIdx.x;   // 8192
    int d = idx & (D_DIM - 1);
    int b = idx >> 11;
    float h = 0.f;
    for (int c0 = 0; c0 < NCH; c0 += 8) {
        float F[8], I[8];
#pragma unroll
        for (int j = 0; j < 8; j++) {
            size_t ci = ((size_t)b * NCH + c0 + j) * D_DIM + d;
            F[j] = Fc[ci];
            I[j] = Ic[ci];
        }
#pragma unroll
        for (int j = 0; j < 8; j++) {
            size_t ci = ((size_t)b * NCH + c0 + j) * D_DIM + d;
            Hc[ci] = h;
            h = F[j] * h + I[j];
        }
    }
}

__global__ void scan3(const bfraw* __restrict__ iL, const bfraw* __restrict__ fL,
                      const float* __restrict__ Hc, bfraw* __restrict__ hout) {
    int idx = blockIdx.x * 256 + threadIdx.x;
    int d = idx & (D_DIM - 1);
    int c = (idx >> 11) & (NCH - 1);
    int b = idx >> 17;
    size_t base = ((size_t)(b * L_DIM + c * CHUNK)) * D_DIM + d;
    float h = Hc[((size_t)b * NCH + c) * D_DIM + d];
#pragma unroll 4
    for (int t = 0; t < CHUNK; t++) {
        size_t a = base + (size_t)t * D_DIM;
        float fr = bf2f(fL[a]);
        float ir = bf2f(iL[a]);
        float fv = sigmoidf_(fr);
        float iv = ir * sigmoidf_(ir) * (1.0f - fv);
        h = fv * h + iv;
        hout[a] = f2bf(h);
    }
}

// ---------------- g-path: o = rmsnorm(g)*gw * h*sigmoid(h); rmsnorm+quant o ---------
union BF8 { uint4 u; bfraw s[8]; };

__global__ void gout_quant(const bfraw* __restrict__ gL, const bfraw* __restrict__ h,
                           const float* __restrict__ gw, int8_t* __restrict__ oq,
                           float* __restrict__ odeq) {
    int row = blockIdx.x, tid = threadIdx.x;
    BF8 g8, h8;
    g8.u = ((const uint4*)(gL + (size_t)row * D_DIM))[tid];
    float gv[8];
    float ss = 0.f;
#pragma unroll
    for (int j = 0; j < 8; j++) { gv[j] = bf2f(g8.s[j]); ss += gv[j] * gv[j]; }
    float ssg = block_sum256(ss);
    float invg = rsqrtf(ssg * (1.0f / (float)D_DIM) + 1e-5f);

    h8.u = ((const uint4*)(h + (size_t)row * D_DIM))[tid];
    const float4* wr = (const float4*)gw;
    float4 w0 = wr[2 * tid], w1 = wr[2 * tid + 1];
    float wv[8] = {w0.x, w0.y, w0.z, w0.w, w1.x, w1.y, w1.z, w1.w};
    float o[8];
    float sso = 0.f, amax = 0.f;
#pragma unroll
    for (int j = 0; j < 8; j++) {
        float hv = bf2f(h8.s[j]);
        o[j] = gv[j] * invg * wv[j] * hv * sigmoidf_(hv);
        sso += o[j] * o[j];
        amax = fmaxf(amax, fabsf(o[j]));
    }
    block_sum_max256(sso, amax);
    float invo = rsqrtf(sso * (1.0f / (float)D_DIM) + 1e-5f);
    float anc = fmaxf(amax * invo, 1e-5f);
    float s = 127.0f / anc;
    if (tid == 0) odeq[row] = anc * (1.0f / 127.0f);
    float sc = invo * s;
    int q[8];
#pragma unroll
    for (int j = 0; j < 8; j++) {
        int t = (int)rintf(o[j] * sc);
        q[j] = t < -128 ? -128 : (t > 127 ? 127 : t);
    }
    uint32_t lo = (uint32_t)(q[0] & 0xff) | ((uint32_t)(q[1] & 0xff) << 8) |
                  ((uint32_t)(q[2] & 0xff) << 16) | ((uint32_t)(q[3] & 0xff) << 24);
    uint32_t hi = (uint32_t)(q[4] & 0xff) | ((uint32_t)(q[5] & 0xff) << 8) |
                  ((uint32_t)(q[6] & 0xff) << 16) | ((uint32_t)(q[7] & 0xff) << 24);
    ((uint2*)(oq + (size_t)row * D_DIM))[tid] = make_uint2(lo, hi);
}

// ---------------- driver ----------------
extern "C" void kernel_launch(void* const* d_in, const int* in_sizes, int n_in,
                              void* d_out, int out_size, void* d_ws, size_t ws_size,
                              hipStream_t stream) {
    const float* x  = (const float*)d_in[0];
    const float* Wi = (const float*)d_in[1];
    const float* Wf = (const float*)d_in[2];
    const float* Wg = (const float*)d_in[3];
    const float* Wo = (const float*)d_in[4];
    const float* gw = (const float*)d_in[5];
    float* out = (float*)d_out;

    char* ws = (char*)d_ws;
    float*  wdeq  = (float*)(ws + 0);                 // 4 floats
    float*  wpart = (float*)(ws + 256);               // 512 partials
    float*  adeq  = (float*)(ws + 0x10000);           // 8192 per-row act dequant
    float*  odeq  = (float*)(ws + 0x20000);           // 8192 per-row o dequant
    int8_t* xq    = (int8_t*)(ws + 0x100000);         // 16MB int8 x; reused as oq
    int8_t* wq    = (int8_t*)(ws + 0x1100000);        // 4 x 4MB ternary weights
    float*  Fc    = (float*)(ws + 0x2100000);         // 2MB chunk f-products
    float*  Ic    = (float*)(ws + 0x2300000);         // 2MB chunk partial h
    float*  Hc    = (float*)(ws + 0x2500000);         // 2MB chunk carries
    bfraw*  bufI  = (bfraw*)(ws + 0x4000000);         // 32MB bf16: i_lin -> g_lin
    bfraw*  bufF  = (bfraw*)(ws + 0x6000000);         // 32MB bf16: f_lin
    bfraw*  hbuf  = (bfraw*)(ws + 0x8000000);         // 32MB bf16: h

    wstats1<<<512, 256, 0, stream>>>(Wi, Wf, Wg, Wo, wpart);
    wstats2<<<1, 256, 0, stream>>>(wpart, wdeq);
    wquant<<<16384, 256, 0, stream>>>(Wi, Wf, Wg, Wo, wdeq, wq);
    act_quant<<<M_DIM, 256, 0, stream>>>(x, xq, adeq);

    dim3 ggrid(N_DIM / BN, M_DIM / BM);
    gemm_i8<bfraw><<<ggrid, 256, 0, stream>>>(xq, wq + 0 * (size_t)WELEM, adeq, wdeq, 0, bufI);
    gemm_i8<bfraw><<<ggrid, 256, 0, stream>>>(xq, wq + 1 * (size_t)WELEM, adeq, wdeq, 1, bufF);

    scan1<<<2048, 256, 0, stream>>>(bufI, bufF, Fc, Ic);
    scan2<<<32, 256, 0, stream>>>(Fc, Ic, Hc);
    scan3<<<2048, 256, 0, stream>>>(bufI, bufF, Hc, hbuf);

    gemm_i8<bfraw><<<ggrid, 256, 0, stream>>>(xq, wq + 2 * (size_t)WELEM, adeq, wdeq, 2, bufI); // g_lin
    gout_quant<<<M_DIM, 256, 0, stream>>>(bufI, hbuf, gw, xq /*as oq*/, odeq);
    gemm_i8<float><<<ggrid, 256, 0, stream>>>(xq /*oq*/, wq + 3 * (size_t)WELEM, odeq, wdeq, 3, out);

    (void)in_sizes; (void)n_in; (void)out_size; (void)ws_size;
}

// Round 3
// 430.920 us; speedup vs baseline: 1.2174x; 1.1440x over previous
//
#include <hip/hip_runtime.h>
#include <stdint.h>

// Problem constants (B=4, L=2048, D=2048)
#define B_DIM 4
#define L_DIM 2048
#define D_DIM 2048
#define M_DIM 8192              // B*L token rows
#define K_DIM 2048
#define N_DIM 2048
#define WELEM (D_DIM * D_DIM)   // 4194304 elements per weight
#define CHUNK 32
#define NCH (L_DIM / CHUNK)     // 64 chunks per sequence

typedef int v4i __attribute__((ext_vector_type(4)));
typedef unsigned short bfraw;   // bf16 bit pattern

#define AS1 __attribute__((address_space(1)))
#define AS3 __attribute__((address_space(3)))

__device__ __forceinline__ void gl_lds16(const void* g, void* l) {
    // async global->LDS, 16B per lane; LDS dst = wave-uniform base + lane*16
    __builtin_amdgcn_global_load_lds((AS1 void*)g, (AS3 void*)l, 16, 0, 0);
}

__device__ __forceinline__ float sigmoidf_(float x) { return 1.0f / (1.0f + expf(-x)); }

__device__ __forceinline__ float bf2f(bfraw u) {
    union { unsigned int i; float f; } c; c.i = ((unsigned int)u) << 16; return c.f;
}
__device__ __forceinline__ bfraw f2bf(float f) {
    union { float f; unsigned int i; } c; c.f = f;
    unsigned int lsb = (c.i >> 16) & 1;
    c.i += 0x7fffu + lsb;                   // round-to-nearest-even
    return (bfraw)(c.i >> 16);
}

__device__ __forceinline__ void store_out(float* p, float v) { *p = v; }
__device__ __forceinline__ void store_out(bfraw* p, float v) { *p = f2bf(v); }

// ---------------- block reductions (256 threads = 4 waves) ----------------
__device__ __forceinline__ float block_sum256(float v) {
#pragma unroll
    for (int off = 32; off > 0; off >>= 1) v += __shfl_down(v, off);
    __shared__ float sb[4];
    int lane = threadIdx.x & 63, wv = threadIdx.x >> 6;
    __syncthreads();
    if (lane == 0) sb[wv] = v;
    __syncthreads();
    return sb[0] + sb[1] + sb[2] + sb[3];
}

__device__ __forceinline__ void block_sum_max256(float& s, float& m) {
#pragma unroll
    for (int off = 32; off > 0; off >>= 1) {
        s += __shfl_down(s, off);
        m = fmaxf(m, __shfl_down(m, off));
    }
    __shared__ float sb2[8];
    int lane = threadIdx.x & 63, wv = threadIdx.x >> 6;
    __syncthreads();
    if (lane == 0) { sb2[wv] = s; sb2[4 + wv] = m; }
    __syncthreads();
    s = sb2[0] + sb2[1] + sb2[2] + sb2[3];
    m = fmaxf(fmaxf(sb2[4], sb2[5]), fmaxf(sb2[6], sb2[7]));
}

// ---------------- weight stats: mean|W| per weight ----------------
__global__ void wstats1(const float* __restrict__ w0, const float* __restrict__ w1,
                        const float* __restrict__ w2, const float* __restrict__ w3,
                        float* __restrict__ wpart) {
    int w = blockIdx.x >> 7;
    int slice = blockIdx.x & 127;
    const float* W = (w == 0) ? w0 : ((w == 1) ? w1 : ((w == 2) ? w2 : w3));
    const float4* p = (const float4*)(W + (size_t)slice * (WELEM / 128));
    float s = 0.f;
    for (int i = threadIdx.x; i < (WELEM / 128 / 4); i += 256) {
        float4 v = p[i];
        s += fabsf(v.x) + fabsf(v.y) + fabsf(v.z) + fabsf(v.w);
    }
    s = block_sum256(s);
    if (threadIdx.x == 0) wpart[blockIdx.x] = s;
}

__global__ void wstats2(const float* __restrict__ wpart, float* __restrict__ wdeq) {
    int w = threadIdx.x >> 6;
    int lane = threadIdx.x & 63;
    float s = wpart[w * 128 + lane] + wpart[w * 128 + 64 + lane];
#pragma unroll
    for (int off = 32; off > 0; off >>= 1) s += __shfl_down(s, off);
    if (lane == 0) wdeq[w] = fmaxf(s * (1.0f / (float)WELEM), 1e-5f);
}

// ---------------- merged: weight ternary quant (blocks 0..16383) + act quant ------
__global__ void quant_all(const float* __restrict__ w0, const float* __restrict__ w1,
                          const float* __restrict__ w2, const float* __restrict__ w3,
                          const float* __restrict__ wdeq, int8_t* __restrict__ wq,
                          const float* __restrict__ x, int8_t* __restrict__ xq,
                          float* __restrict__ adeq) {
    if (blockIdx.x < 16384) {
        // ----- weight ternary quantization: one float4 group per thread -----
        size_t idx = (size_t)blockIdx.x * 256 + threadIdx.x;
        int w = (int)(idx >> 20);                               // WELEM/4 = 2^20 groups/weight
        size_t g = idx & ((1u << 20) - 1);
        const float* W = (w == 0) ? w0 : ((w == 1) ? w1 : ((w == 2) ? w2 : w3));
        float inv = 1.0f / wdeq[w];                             // = ws
        float4 v = ((const float4*)W)[g];
        int q0 = (int)rintf(v.x * inv); q0 = q0 < -1 ? -1 : (q0 > 1 ? 1 : q0);
        int q1 = (int)rintf(v.y * inv); q1 = q1 < -1 ? -1 : (q1 > 1 ? 1 : q1);
        int q2 = (int)rintf(v.z * inv); q2 = q2 < -1 ? -1 : (q2 > 1 ? 1 : q2);
        int q3 = (int)rintf(v.w * inv); q3 = q3 < -1 ? -1 : (q3 > 1 ? 1 : q3);
        uint32_t p = (uint32_t)(q0 & 0xff) | ((uint32_t)(q1 & 0xff) << 8) |
                     ((uint32_t)(q2 & 0xff) << 16) | ((uint32_t)(q3 & 0xff) << 24);
        ((uint32_t*)(wq + (size_t)w * WELEM))[g] = p;
        return;
    }
    // ----- activation rmsnorm + int8 quant (one row per block) -----
    int row = blockIdx.x - 16384, tid = threadIdx.x;
    const float4* xr = (const float4*)(x + (size_t)row * D_DIM);
    float4 a = xr[2 * tid], b = xr[2 * tid + 1];
    float v[8] = {a.x, a.y, a.z, a.w, b.x, b.y, b.z, b.w};
    float ss = 0.f, mx = 0.f;
#pragma unroll
    for (int j = 0; j < 8; j++) { ss += v[j] * v[j]; mx = fmaxf(mx, fabsf(v[j])); }
    block_sum_max256(ss, mx);
    float inv = rsqrtf(ss * (1.0f / (float)D_DIM) + 1e-5f);
    float anc = fmaxf(mx * inv, 1e-5f);      // max|xn| clipped
    float s = 127.0f / anc;
    if (tid == 0) adeq[row] = anc * (1.0f / 127.0f);
    float sc = inv * s;
    int q[8];
#pragma unroll
    for (int j = 0; j < 8; j++) {
        int t = (int)rintf(v[j] * sc);
        q[j] = t < -128 ? -128 : (t > 127 ? 127 : t);
    }
    uint32_t lo = (uint32_t)(q[0] & 0xff) | ((uint32_t)(q[1] & 0xff) << 8) |
                  ((uint32_t)(q[2] & 0xff) << 16) | ((uint32_t)(q[3] & 0xff) << 24);
    uint32_t hi = (uint32_t)(q[4] & 0xff) | ((uint32_t)(q[5] & 0xff) << 8) |
                  ((uint32_t)(q[6] & 0xff) << 16) | ((uint32_t)(q[7] & 0xff) << 24);
    ((uint2*)(xq + (size_t)row * D_DIM))[tid] = make_uint2(lo, hi);
}

// ---------------- int8 x ternary GEMM core: 128x256 tile, BK=64B, 4 waves ---------
// wave wv: wm=(wv&1)*64, wn=(wv>>1)*128 -> 64x128 per wave, 4 afrag + 8 bfrag,
// 32 mfma_i32_16x16x64_i8 per K-iter. LDS row stride 64B (2-way-conflict pattern).
#define BM 128
#define BN 256
#define BKB 64

template <typename OutT>
__device__ __forceinline__ void gemm_core(
    const int8_t* __restrict__ A, const int8_t* __restrict__ Bw,
    const float* __restrict__ adeq, float wsc,
    int m0, int n0, OutT* __restrict__ Cout) {
    __shared__ int8_t sA[BM * BKB];   // 8 KB
    __shared__ int8_t sB[BN * BKB];   // 16 KB
    int lane = threadIdx.x & 63;
    int wv = threadIdx.x >> 6;
    int wm = (wv & 1) * 64;
    int wn = (wv >> 1) * 128;

    const v4i vzero = {0, 0, 0, 0};
    v4i acc[4][8];
#pragma unroll
    for (int i = 0; i < 4; i++)
#pragma unroll
        for (int j = 0; j < 8; j++) acc[i][j] = vzero;

    int rS = lane >> 2;             // row within 16-row group
    int cS = (lane & 3) * 16;       // byte col within 64
    const int8_t* Ablk = A + (size_t)m0 * K_DIM;
    const int8_t* Bblk = Bw + (size_t)n0 * K_DIM;
    int qq = lane >> 4;             // quad
    int mr = lane & 15;

    for (int kt = 0; kt < K_DIM; kt += BKB) {
        // stage A (128 rows) + B (256 rows): 6 insts/wave, 1 KB each
        gl_lds16(Ablk + (size_t)(wv * 16 + rS) * K_DIM + kt + cS, sA + (wv * 16) * BKB);
        gl_lds16(Ablk + (size_t)(64 + wv * 16 + rS) * K_DIM + kt + cS, sA + (64 + wv * 16) * BKB);
#pragma unroll
        for (int g = 0; g < 4; g++) {
            int rb = g * 64 + wv * 16;
            gl_lds16(Bblk + (size_t)(rb + rS) * K_DIM + kt + cS, sB + rb * BKB);
        }
        __syncthreads();

        v4i afrag[4], bfrag[8];
#pragma unroll
        for (int i = 0; i < 4; i++)
            afrag[i] = *(const v4i*)(sA + (size_t)(wm + i * 16 + mr) * BKB + qq * 16);
#pragma unroll
        for (int j = 0; j < 8; j++)
            bfrag[j] = *(const v4i*)(sB + (size_t)(wn + j * 16 + mr) * BKB + qq * 16);
#pragma unroll
        for (int i = 0; i < 4; i++)
#pragma unroll
            for (int j = 0; j < 8; j++)
                acc[i][j] = __builtin_amdgcn_mfma_i32_16x16x64_i8(afrag[i], bfrag[j], acc[i][j], 0, 0, 0);
        __syncthreads();
    }

    int cc = lane & 15;
#pragma unroll
    for (int i = 0; i < 4; i++) {
#pragma unroll
        for (int r = 0; r < 4; r++) {
            int row = m0 + wm + i * 16 + qq * 4 + r;   // C/D: row = quad*4 + reg
            float rs = adeq[row] * wsc;
            OutT* crow = Cout + (size_t)row * N_DIM + n0 + wn + cc;
#pragma unroll
            for (int j = 0; j < 8; j++) store_out(crow + j * 16, (float)acc[i][j][r] * rs);
        }
    }
}

// merged i/f/g GEMM: grid.x = 24 (8 N-tiles x 3 weights), grid.y = 64 M-tiles
__global__ __launch_bounds__(256, 2) void gemm_ifg(
    const int8_t* __restrict__ xq, const int8_t* __restrict__ wq,
    const float* __restrict__ adeq, const float* __restrict__ wdeq,
    bfraw* __restrict__ bufI, bfraw* __restrict__ bufF, bfraw* __restrict__ bufG) {
    int widx = blockIdx.x >> 3;
    int n0 = (blockIdx.x & 7) * BN;
    int m0 = blockIdx.y * BM;
    bfraw* outp = (widx == 0) ? bufI : ((widx == 1) ? bufF : bufG);
    gemm_core<bfraw>(xq, wq + (size_t)widx * WELEM, adeq, wdeq[widx], m0, n0, outp);
}

// final o GEMM: fp32 out. grid.x = 8, grid.y = 64
__global__ __launch_bounds__(256, 2) void gemm_o(
    const int8_t* __restrict__ oq, const int8_t* __restrict__ wq,
    const float* __restrict__ odeq, const float* __restrict__ wdeq,
    float* __restrict__ out) {
    gemm_core<float>(oq, wq + 3 * (size_t)WELEM, odeq, wdeq[3], blockIdx.y * BM,
                     blockIdx.x * BN, out);
}

// ---------------- chunked scan with fused activations ----------------
// f_t = sigmoid(fL_t); i_t = silu(iL_t)*(1-f_t); h_t = f_t*h_{t-1} + i_t
__global__ void scan1(const bfraw* __restrict__ iL, const bfraw* __restrict__ fL,
                      float* __restrict__ Fc, float* __restrict__ Ic) {
    int idx = blockIdx.x * 256 + threadIdx.x;   // 4*64*2048
    int d = idx & (D_DIM - 1);
    int c = (idx >> 11) & (NCH - 1);
    int b = idx >> 17;
    size_t base = ((size_t)(b * L_DIM + c * CHUNK)) * D_DIM + d;
    float F = 1.f, h = 0.f;
#pragma unroll 4
    for (int t = 0; t < CHUNK; t++) {
        float fr = bf2f(fL[base + (size_t)t * D_DIM]);
        float ir = bf2f(iL[base + (size_t)t * D_DIM]);
        float fv = sigmoidf_(fr);
        float iv = ir * sigmoidf_(ir) * (1.0f - fv);
        h = fv * h + iv;
        F *= fv;
    }
    size_t ci = ((size_t)b * NCH + c) * D_DIM + d;
    Fc[ci] = F;
    Ic[ci] = h;
}

__global__ void scan2(const float* __restrict__ Fc, const float* __restrict__ Ic,
                      float* __restrict__ Hc) {
    int idx = blockIdx.x * 256 + threadIdx.x;   // 8192
    int d = idx & (D_DIM - 1);
    int b = idx >> 11;
    float h = 0.f;
    for (int c0 = 0; c0 < NCH; c0 += 8) {
        float F[8], I[8];
#pragma unroll
        for (int j = 0; j < 8; j++) {
            size_t ci = ((size_t)b * NCH + c0 + j) * D_DIM + d;
            F[j] = Fc[ci];
            I[j] = Ic[ci];
        }
#pragma unroll
        for (int j = 0; j < 8; j++) {
            size_t ci = ((size_t)b * NCH + c0 + j) * D_DIM + d;
            Hc[ci] = h;
            h = F[j] * h + I[j];
        }
    }
}

__global__ void scan3(const bfraw* __restrict__ iL, const bfraw* __restrict__ fL,
                      const float* __restrict__ Hc, bfraw* __restrict__ hout) {
    int idx = blockIdx.x * 256 + threadIdx.x;
    int d = idx & (D_DIM - 1);
    int c = (idx >> 11) & (NCH - 1);
    int b = idx >> 17;
    size_t base = ((size_t)(b * L_DIM + c * CHUNK)) * D_DIM + d;
    float h = Hc[((size_t)b * NCH + c) * D_DIM + d];
#pragma unroll 4
    for (int t = 0; t < CHUNK; t++) {
        size_t a = base + (size_t)t * D_DIM;
        float fr = bf2f(fL[a]);
        float ir = bf2f(iL[a]);
        float fv = sigmoidf_(fr);
        float iv = ir * sigmoidf_(ir) * (1.0f - fv);
        h = fv * h + iv;
        hout[a] = f2bf(h);
    }
}

// ---------------- g-path: o = rmsnorm(g)*gw * h*sigmoid(h); rmsnorm+quant o ---------
union BF8 { uint4 u; bfraw s[8]; };

__global__ void gout_quant(const bfraw* __restrict__ gL, const bfraw* __restrict__ h,
                           const float* __restrict__ gw, int8_t* __restrict__ oq,
                           float* __restrict__ odeq) {
    int row = blockIdx.x, tid = threadIdx.x;
    BF8 g8, h8;
    g8.u = ((const uint4*)(gL + (size_t)row * D_DIM))[tid];
    float gv[8];
    float ss = 0.f;
#pragma unroll
    for (int j = 0; j < 8; j++) { gv[j] = bf2f(g8.s[j]); ss += gv[j] * gv[j]; }
    float ssg = block_sum256(ss);
    float invg = rsqrtf(ssg * (1.0f / (float)D_DIM) + 1e-5f);

    h8.u = ((const uint4*)(h + (size_t)row * D_DIM))[tid];
    const float4* wr = (const float4*)gw;
    float4 w0 = wr[2 * tid], w1 = wr[2 * tid + 1];
    float wv[8] = {w0.x, w0.y, w0.z, w0.w, w1.x, w1.y, w1.z, w1.w};
    float o[8];
    float sso = 0.f, amax = 0.f;
#pragma unroll
    for (int j = 0; j < 8; j++) {
        float hv = bf2f(h8.s[j]);
        o[j] = gv[j] * invg * wv[j] * hv * sigmoidf_(hv);
        sso += o[j] * o[j];
        amax = fmaxf(amax, fabsf(o[j]));
    }
    block_sum_max256(sso, amax);
    float invo = rsqrtf(sso * (1.0f / (float)D_DIM) + 1e-5f);
    float anc = fmaxf(amax * invo, 1e-5f);
    float s = 127.0f / anc;
    if (tid == 0) odeq[row] = anc * (1.0f / 127.0f);
    float sc = invo * s;
    int q[8];
#pragma unroll
    for (int j = 0; j < 8; j++) {
        int t = (int)rintf(o[j] * sc);
        q[j] = t < -128 ? -128 : (t > 127 ? 127 : t);
    }
    uint32_t lo = (uint32_t)(q[0] & 0xff) | ((uint32_t)(q[1] & 0xff) << 8) |
                  ((uint32_t)(q[2] & 0xff) << 16) | ((uint32_t)(q[3] & 0xff) << 24);
    uint32_t hi = (uint32_t)(q[4] & 0xff) | ((uint32_t)(q[5] & 0xff) << 8) |
                  ((uint32_t)(q[6] & 0xff) << 16) | ((uint32_t)(q[7] & 0xff) << 24);
    ((uint2*)(oq + (size_t)row * D_DIM))[tid] = make_uint2(lo, hi);
}

// ---------------- driver ----------------
extern "C" void kernel_launch(void* const* d_in, const int* in_sizes, int n_in,
                              void* d_out, int out_size, void* d_ws, size_t ws_size,
                              hipStream_t stream) {
    const float* x  = (const float*)d_in[0];
    const float* Wi = (const float*)d_in[1];
    const float* Wf = (const float*)d_in[2];
    const float* Wg = (const float*)d_in[3];
    const float* Wo = (const float*)d_in[4];
    const float* gw = (const float*)d_in[5];
    float* out = (float*)d_out;

    char* ws = (char*)d_ws;
    float*  wdeq  = (float*)(ws + 0);                 // 4 floats
    float*  wpart = (float*)(ws + 256);               // 512 partials
    float*  adeq  = (float*)(ws + 0x10000);           // 8192 per-row act dequant
    float*  odeq  = (float*)(ws + 0x20000);           // 8192 per-row o dequant
    int8_t* xq    = (int8_t*)(ws + 0x100000);         // 16MB int8 x; reused as oq
    int8_t* wq    = (int8_t*)(ws + 0x1100000);        // 4 x 4MB ternary weights
    float*  Fc    = (float*)(ws + 0x2100000);         // 2MB chunk f-products
    float*  Ic    = (float*)(ws + 0x2300000);         // 2MB chunk partial h
    float*  Hc    = (float*)(ws + 0x2500000);         // 2MB chunk carries
    bfraw*  bufI  = (bfraw*)(ws + 0x4000000);         // 32MB bf16: i_lin
    bfraw*  bufF  = (bfraw*)(ws + 0x6000000);         // 32MB bf16: f_lin
    bfraw*  bufG  = (bfraw*)(ws + 0x8000000);         // 32MB bf16: g_lin
    bfraw*  hbuf  = (bfraw*)(ws + 0xA000000);         // 32MB bf16: h

    wstats1<<<512, 256, 0, stream>>>(Wi, Wf, Wg, Wo, wpart);
    wstats2<<<1, 256, 0, stream>>>(wpart, wdeq);
    quant_all<<<16384 + 8192, 256, 0, stream>>>(Wi, Wf, Wg, Wo, wdeq, wq, x, xq, adeq);

    gemm_ifg<<<dim3(24, M_DIM / BM), 256, 0, stream>>>(xq, wq, adeq, wdeq, bufI, bufF, bufG);

    scan1<<<2048, 256, 0, stream>>>(bufI, bufF, Fc, Ic);
    scan2<<<32, 256, 0, stream>>>(Fc, Ic, Hc);
    scan3<<<2048, 256, 0, stream>>>(bufI, bufF, Hc, hbuf);

    gout_quant<<<M_DIM, 256, 0, stream>>>(bufG, hbuf, gw, xq /*as oq*/, odeq);
    gemm_o<<<dim3(N_DIM / BN, M_DIM / BM), 256, 0, stream>>>(xq /*oq*/, wq, odeq, wdeq, out);

    (void)in_sizes; (void)n_in; (void)out_size; (void)ws_size;
}